// Round 15
// baseline (46.504 us; speedup 1.0000x reference)
//
#include <hip/hip_runtime.h>
#include <math.h>

#define TS 49
#define LOG49 3.8918202981106265f
#define LN2 0.6931471805599453f

typedef short bf16x8 __attribute__((ext_vector_type(8)));  // 8 bf16 = 4 VGPRs
typedef float f32x4 __attribute__((ext_vector_type(4)));
typedef float f32x4u __attribute__((ext_vector_type(4), aligned(4)));
typedef unsigned u32x4 __attribute__((ext_vector_type(4)));

// Position labeling: position p holds original state (p+1)%49 -> emission col = p.
// E stored as the A-operand of D = E * V (rows = pos_out, cols(k) = pos_in with
// custom labeling kappa chosen so D's C-layout IS the next step's B-fragment):
//   A row r = 16*nt + (lane&15); hw k = 32h + 8*(lane>>4) + s
//   kappa(32h + 8G + s) = 32h + 16*(s>>2) + 4G + (s&3)
// ws layout: bf16[nt=4][h=2][lane=64][s=8] (8 KB), then float Tmax at byte 8192.

__global__ void prep_kernel(const float* __restrict__ tf, const float* __restrict__ w2,
                            const float* __restrict__ b2, float* __restrict__ ws) {
    __shared__ float tr[TS * TS];
    __shared__ float red[256];
    const int tid = threadIdx.x;
    const float w0 = w2[0], w1 = w2[1], w2v = w2[2], w3 = w2[3], w4 = w2[4], w5 = w2[5];
    const float bb = b2[0];
    float lmax = -INFINITY;
    for (int idx = tid; idx < TS * TS; idx += 256) {
        const float* p = tf + idx * 6;
        float s = bb + p[0]*w0 + p[1]*w1 + p[2]*w2v + p[3]*w3 + p[4]*w4 + p[5]*w5;
        tr[idx] = s;
        lmax = fmaxf(lmax, s);
    }
    red[tid] = lmax;
    __syncthreads();
    for (int s = 128; s > 0; s >>= 1) {
        if (tid < s) red[tid] = fmaxf(red[tid], red[tid + s]);
        __syncthreads();
    }
    const float Tmax = red[0];
    __syncthreads();
    unsigned short* B = (unsigned short*)ws;
    for (int idx = tid; idx < 4096; idx += 256) {
        const int s  = idx & 7;
        const int l  = (idx >> 3) & 63;
        const int h  = (idx >> 9) & 1;
        const int nt = idx >> 10;
        const int G  = l >> 4, c0 = l & 15;
        const int r  = 16 * nt + c0;                              // output position
        const int kp = 32 * h + 16 * (s >> 2) + 4 * G + (s & 3);  // input position
        float v = 0.0f;
        if (r < TS && kp < TS) {
            const int jj = (r + 1) % TS, kk = (kp + 1) % TS;
            v = __expf(tr[jj * TS + kk] - Tmax);
        }
        unsigned bts = __float_as_uint(v);
        B[idx] = (unsigned short)((bts + 0x7FFFu + ((bts >> 16) & 1u)) >> 16);  // rne bf16
    }
    if (tid == 0) ((float*)ws)[2048] = Tmax;  // byte 8192
}

__device__ __forceinline__ unsigned cvtpk_bf16(float lo, float hi) {
    unsigned d;  // D[15:0]=bf16(lo), D[31:16]=bf16(hi)
    asm("v_cvt_pk_bf16_f32 %0, %1, %2" : "=v"(d) : "v"(lo), "v"(hi));
    return d;
}

// One wave = 4 chains (chain = (lane&15)&3; MFMA columns 4..15 compute redundant
// copies -- matrix pipe has headroom, redundancy buys 4x the wave count).
// State in C-layout regs v[nt][t]: position 16nt + 4G + t (G = lane>>4), col c0.
// No LDS, no cross-lane in the loop: the C-layout fragment is bit-identical
// (after bf16 pack) to the next step's B-fragment under the kappa labeling.
__global__ __launch_bounds__(64, 2) void crf_fwd(const float* __restrict__ emis,
                                                 const unsigned short* __restrict__ wsE,
                                                 float* __restrict__ out, int L) {
    const int l = threadIdx.x, G = l >> 4, c0 = l & 15;
    const int b0 = blockIdx.x * 4;
    const float Tmax = ((const float*)wsE)[2048];

    // E A-fragments, register-resident
    bf16x8 E[4][2];
    {
        const bf16x8* Et = (const bf16x8*)wsE;
        #pragma unroll
        for (int nt = 0; nt < 4; ++nt)
            #pragma unroll
            for (int h = 0; h < 2; ++h) E[nt][h] = Et[(nt * 2 + h) * 64 + l];
    }

    // Emission bases: chain c0&3, col chunks {4G, 16+4G, 32+4G, 45} (all in-row).
    const int LT = L * TS;
    const float* const ebase = emis + (size_t)(b0 + (c0 & 3)) * LT;
    const int cb[4] = {4 * G, 16 + 4 * G, 32 + 4 * G, 45};

    f32x4 pf[4][4];  // [slot][nt], statically indexed only

#define LQ(STEP, SLOT) do {                                                           \
    const int _o = (STEP) * TS;                                                       \
    pf[SLOT][0] = *(const f32x4u*)(ebase + _o + cb[0]);                               \
    pf[SLOT][1] = *(const f32x4u*)(ebase + _o + cb[1]);                               \
    pf[SLOT][2] = *(const f32x4u*)(ebase + _o + cb[2]);                               \
    pf[SLOT][3] = *(const f32x4u*)(ebase + _o + cb[3]);                               \
} while (0)

    // ee for a step: nt<=2 all live (pos <= 47); nt=3: only (G=0,t=0)=pos48 matters,
    // its value sits at elem 3 of the col-45 chunk; dead entries get e3 too (acc=0).
#define EESEL(DST, SLOT) do {                                                         \
    _Pragma("unroll")                                                                 \
    for (int t = 0; t < 4; ++t) {                                                     \
        DST[0][t] = __expf(pf[SLOT][0][t]);                                           \
        DST[1][t] = __expf(pf[SLOT][1][t]);                                           \
        DST[2][t] = __expf(pf[SLOT][2][t]);                                           \
    }                                                                                 \
    const float e3_ = __expf(pf[SLOT][3].w);                                          \
    _Pragma("unroll")                                                                 \
    for (int t = 0; t < 4; ++t) DST[3][t] = e3_;                                      \
} while (0)

    f32x4 acc[4];      // E @ V_{I-1}, tile nt
    float v[4][4];     // V_I
    float ee0[4][4], ee1[4][4];
    float sc = 0.f, fac = 1.f, pend = 0.f;

    // pack v (C-layout) -> B-frags (identity relabeling) + 8 MFMAs -> acc
#define PACKMM() do {                                                                 \
    u32x4 Bu0, Bu1;                                                                   \
    Bu0.x = cvtpk_bf16(v[0][0], v[0][1]);                                             \
    Bu0.y = cvtpk_bf16(v[0][2], v[0][3]);                                             \
    Bu0.z = cvtpk_bf16(v[1][0], v[1][1]);                                             \
    Bu0.w = cvtpk_bf16(v[1][2], v[1][3]);                                             \
    Bu1.x = cvtpk_bf16(v[2][0], v[2][1]);                                             \
    Bu1.y = cvtpk_bf16(v[2][2], v[2][3]);                                             \
    Bu1.z = cvtpk_bf16(v[3][0], v[3][1]);                                             \
    Bu1.w = cvtpk_bf16(v[3][2], v[3][3]);                                             \
    const bf16x8 B0 = __builtin_bit_cast(bf16x8, Bu0);                                \
    const bf16x8 B1 = __builtin_bit_cast(bf16x8, Bu1);                                \
    const f32x4 z_ = {0.f, 0.f, 0.f, 0.f};                                            \
    _Pragma("unroll")                                                                 \
    for (int nt = 0; nt < 4; ++nt) {                                                  \
        f32x4 a = __builtin_amdgcn_mfma_f32_16x16x32_bf16(E[nt][0], B0, z_, 0, 0, 0); \
        a = __builtin_amdgcn_mfma_f32_16x16x32_bf16(E[nt][1], B1, a, 0, 0, 0);        \
        acc[nt] = a;                                                                  \
    }                                                                                 \
} while (0)

#define RENC() do {                                                                   \
    float mx = v[0][0];                                                               \
    _Pragma("unroll")                                                                 \
    for (int nt = 0; nt < 4; ++nt)                                                    \
        _Pragma("unroll")                                                             \
        for (int t = 0; t < 4; ++t) mx = fmaxf(mx, v[nt][t]);                         \
    mx = fmaxf(mx, __shfl_xor(mx, 16, 64));                                           \
    mx = fmaxf(mx, __shfl_xor(mx, 32, 64));                                           \
    const unsigned ex = __float_as_uint(mx) >> 23;                                    \
    fac  = __uint_as_float((254u - ex) << 23);                                        \
    pend = (float)((int)ex - 127) * LN2;                                              \
} while (0)

#define STEP(I, EC, EN, SN, SL, DO_C, DO_A) do {                                      \
    if ((I) + 3 < L) LQ((I) + 3, SL);        /* earliest issue -> max slack */        \
    _Pragma("unroll")                                                                 \
    for (int nt = 0; nt < 4; ++nt)                                                    \
        _Pragma("unroll")                                                             \
        for (int t = 0; t < 4; ++t) {                                                 \
            float nv = acc[nt][t] * EC[nt][t];                                        \
            if (DO_A) nv *= fac;                                                      \
            v[nt][t] = nv;                                                            \
        }                                                                             \
    if (DO_A) sc += pend;                                                             \
    PACKMM();                                                                         \
    EESEL(EN, SN);      /* exps overlap MFMA execution */                             \
    asm volatile("" ::: "memory");  /* anchor this step's loads */                    \
    if (DO_C) RENC();                                                                 \
} while (0)

    // prologue: slots 0..3 = steps 0..3
    LQ(0, 0);
    if (L > 1) LQ(1, 1);
    if (L > 2) LQ(2, 2);
    if (L > 3) LQ(3, 3);

    // init V_0 = exp(emit[0][pos]); dead positions (49..63) = 0
    #pragma unroll
    for (int t = 0; t < 4; ++t) {
        v[0][t] = __expf(pf[0][0][t]);
        v[1][t] = __expf(pf[0][1][t]);
        v[2][t] = __expf(pf[0][2][t]);
        v[3][t] = (G == 0 && t == 0) ? __expf(pf[0][3].w) : 0.0f;
    }
    EESEL(ee1, 1);  // ee for step 1
    PACKMM();       // acc = E @ V_0
    asm volatile("" ::: "memory");

    const int S = L - 1;  // steps 1..S
    int i = 1;
    for (; i + 3 <= S; i += 4) {  // i == 1 mod 4 -> static pf slots
        STEP(i + 0, ee1, ee0, 2, 0, 1, 0);
        STEP(i + 1, ee0, ee1, 3, 1, 0, 1);
        STEP(i + 2, ee1, ee0, 0, 2, 0, 0);
        STEP(i + 3, ee0, ee1, 1, 3, 0, 0);
    }
    if (i <= S)     STEP(i,     ee1, ee0, 2, 0, 1, 0);
    if (i + 1 <= S) STEP(i + 1, ee0, ee1, 3, 1, 0, 1);
    if (i + 2 <= S) STEP(i + 2, ee1, ee0, 0, 2, 0, 0);
#undef STEP
#undef RENC
#undef PACKMM
#undef EESEL
#undef LQ

    // final: alpha[chain] = sc + log(sum_pos V) + LOG49 + (L-1)*Tmax
    float s = 0.0f;
    #pragma unroll
    for (int nt = 0; nt < 4; ++nt)
        #pragma unroll
        for (int t = 0; t < 4; ++t) s += v[nt][t];
    s += __shfl_xor(s, 16, 64);
    s += __shfl_xor(s, 32, 64);
    const float res = sc + __logf(s) + LOG49 + (float)(L - 1) * Tmax;
    if (l < 4) out[b0 + l] = res;
}

extern "C" void kernel_launch(void* const* d_in, const int* in_sizes, int n_in,
                              void* d_out, int out_size, void* d_ws, size_t ws_size,
                              hipStream_t stream) {
    const float* emis = (const float*)d_in[0];
    const float* tf   = (const float*)d_in[1];
    const float* w2   = (const float*)d_in[2];
    const float* b2   = (const float*)d_in[3];
    float* out = (float*)d_out;
    float* ws  = (float*)d_ws;

    const int B = out_size;                // 8192
    const int L = in_sizes[0] / (B * TS);  // 48

    prep_kernel<<<1, 256, 0, stream>>>(tf, w2, b2, ws);
    crf_fwd<<<B / 4, 64, 0, stream>>>(emis, (const unsigned short*)ws, out, L);
}

// Round 16
// 41.628 us; speedup vs baseline: 1.1171x; 1.1171x over previous
//
#include <hip/hip_runtime.h>
#include <math.h>

#define TS 49
#define LOG49 3.8918202981106265f
#define LN2 0.6931471805599453f

typedef short bf16x8 __attribute__((ext_vector_type(8)));  // 8 bf16 = 4 VGPRs
typedef float f32x4 __attribute__((ext_vector_type(4)));

// State relabeling: position p holds original state (p+1)%49 -> emission col = p.
// ws layout (identical to R8/R12/R13):
//   bytes [0, 8192): B-fragments bf16[nt=4][h=2][lane=64][s=8]
//     value = exp(trans[(jp+1)%49][(kp+1)%49] - Tmax), jp = 4*(lane&15)+nt (out pos),
//     kp = 32*h + 8*(lane>>4) + s (in pos); zero outside jp<49 && kp<49.
//   byte 8192: float Tmax

__global__ void prep_kernel(const float* __restrict__ tf, const float* __restrict__ w2,
                            const float* __restrict__ b2, float* __restrict__ ws) {
    __shared__ float tr[TS * TS];
    __shared__ float red[256];
    const int tid = threadIdx.x;
    const float w0 = w2[0], w1 = w2[1], w2v = w2[2], w3 = w2[3], w4 = w2[4], w5 = w2[5];
    const float bb = b2[0];
    float lmax = -INFINITY;
    for (int idx = tid; idx < TS * TS; idx += 256) {
        const float* p = tf + idx * 6;
        float s = bb + p[0]*w0 + p[1]*w1 + p[2]*w2v + p[3]*w3 + p[4]*w4 + p[5]*w5;
        tr[idx] = s;
        lmax = fmaxf(lmax, s);
    }
    red[tid] = lmax;
    __syncthreads();
    for (int s = 128; s > 0; s >>= 1) {
        if (tid < s) red[tid] = fmaxf(red[tid], red[tid + s]);
        __syncthreads();
    }
    const float Tmax = red[0];
    __syncthreads();
    unsigned short* B = (unsigned short*)ws;
    for (int idx = tid; idx < 4096; idx += 256) {
        const int s  = idx & 7;
        const int l  = (idx >> 3) & 63;
        const int h  = (idx >> 9) & 1;
        const int nt = idx >> 10;
        const int jp = 4 * (l & 15) + nt;
        const int kp = 32 * h + 8 * (l >> 4) + s;
        float v = 0.0f;
        if (jp < TS && kp < TS) {
            const int jj = (jp + 1) % TS, kk = (kp + 1) % TS;
            v = __expf(tr[jj * TS + kk] - Tmax);
        }
        unsigned bts = __float_as_uint(v);
        B[idx] = (unsigned short)((bts + 0x7FFFu + ((bts >> 16) & 1u)) >> 16);  // rne bf16
    }
    if (tid == 0) ((float*)ws)[2048] = Tmax;  // byte 8192
}

__device__ __forceinline__ unsigned cvtpk_bf16(float lo, float hi) {
    unsigned d;  // D[15:0]=bf16(lo), D[31:16]=bf16(hi)
    asm("v_cvt_pk_bf16_f32 %0, %1, %2" : "=v"(d) : "v"(lo), "v"(hi));
    return d;
}

// One wave = 4 chains (chain = b0 + (lane>>4)). Position p = 4*(lane&15)+nt.
// V16: chain-major [16][64 bf16], XOR-swizzled (validated, 0 bank conflicts).
// Emissions: 8-slot LDS ring filled by global_load_lds DMA (no VGPR landing ->
// no AGPR parking -> no vmcnt-at-issue); consumption gated by counted vmcnt(16),
// keeping 4 steps (~1600 cy) of loads in flight across the loop.
__global__ __launch_bounds__(64, 4) void crf_fwd(const float* __restrict__ emis,
                                                 const unsigned short* __restrict__ wsB,
                                                 float* __restrict__ out, int L) {
    __shared__ __align__(16) unsigned short V16[1024];  // 2 KB
    __shared__ __align__(16) float EMIS[2048];          // 8 KB: 8 slots x 256 floats
    const int l = threadIdx.x, g = l >> 4, c0 = l & 15;
    const int b0 = blockIdx.x * 4;
    const float Tmax = ((const float*)wsB)[2048];

    // E fragments (B-operand), register-resident
    bf16x8 Bf[4][2];
    {
        const bf16x8* Bt = (const bf16x8*)wsB;
        #pragma unroll
        for (int nt = 0; nt < 4; ++nt)
            #pragma unroll
            for (int h = 0; h < 2; ++h) Bf[nt][h] = Bt[(nt * 2 + h) * 64 + l];
    }

    // V16 LDS indices (validated swizzle)
    int wi[4];
    #pragma unroll
    for (int t = 0; t < 4; ++t) {
        const int ch = 4 * g + t;
        wi[t] = ch * 16 + (c0 ^ ((ch & 7) << 1));  // uint2 units
    }
    const int ra0 = c0 * 8 + (g ^ (c0 & 7));        // bf16x8 units, k 0..31
    const int ra1 = c0 * 8 + ((4 + g) ^ (c0 & 7));  // k 32..63
    uint2* const Vw = (uint2*)V16;
    const bf16x8* const Vr = (const bf16x8*)V16;

    // zero dead internal rows (t=1..3) once
    {
        const uint2 z = {0u, 0u};
        Vw[wi[1]] = z;
        Vw[wi[2]] = z;
        Vw[wi[3]] = z;
    }

    // Per-lane emission source base: chain b0+g, cols col4..col4+3 (edge clamp 45).
    const int LT = L * TS;
    const bool sel12 = (c0 >= 12);
    const int col4 = sel12 ? 45 : 4 * c0;
    const float* const eb = emis + (size_t)(b0 + g) * LT + col4;

    // DMA one step's emissions (4 floats/lane, SoA: float j at slot*256 + j*64 + lane)
#define GLL(STEP_) do {                                                               \
    const float* _s = eb + (STEP_) * TS;                                              \
    float* _d = &EMIS[((STEP_) & 7) << 8];                                            \
    _Pragma("unroll")                                                                 \
    for (int j = 0; j < 4; ++j)                                                       \
        __builtin_amdgcn_global_load_lds(                                             \
            (const __attribute__((address_space(1))) void*)(_s + j),                  \
            (__attribute__((address_space(3))) void*)(_d + j * 64), 4, 0, 0);         \
} while (0)

#define EESEL(DST, STEP_) do {                                                        \
    const float* _p = &EMIS[((STEP_) & 7) << 8];                                      \
    const float q0 = _p[l];                                                           \
    const float q1 = _p[64 + l];                                                      \
    const float q2 = _p[128 + l];                                                     \
    const float q3 = _p[192 + l];                                                     \
    DST[0] = __expf(sel12 ? q3 : q0);                                                 \
    DST[1] = __expf(q1);                                                              \
    DST[2] = __expf(q2);                                                              \
    DST[3] = __expf(q3);                                                              \
} while (0)

    // prologue: stage steps 0..5 (24 DMA ops outstanding)
    GLL(0);
    if (L > 1) GLL(1);
    if (L > 2) GLL(2);
    if (L > 3) GLL(3);
    if (L > 4) GLL(4);
    if (L > 5) GLL(5);

    // init V_0 from slot 0 (wait: keep slots 1..5 = 20 ops in flight)
    float v[4];
    asm volatile("s_waitcnt vmcnt(20)" ::: "memory");
    {
        const float* _p = &EMIS[0];
        const float q0 = _p[l], q1 = _p[64 + l], q2 = _p[128 + l], q3 = _p[192 + l];
        const float i0 = sel12 ? q3 : q0;
        v[0] = (4 * c0 + 0 < TS) ? __expf(i0) : 0.0f;
        v[1] = (4 * c0 + 1 < TS) ? __expf(q1) : 0.0f;
        v[2] = (4 * c0 + 2 < TS) ? __expf(q2) : 0.0f;
        v[3] = (4 * c0 + 3 < TS) ? __expf(q3) : 0.0f;
    }
    float ee0[4], ee1[4];
    asm volatile("s_waitcnt vmcnt(16)" ::: "memory");
    EESEL(ee1, 1);  // emissions for step 1

    float sc = 0.f, fac = 1.f, pend = 0.f;

#define STEP(I, EC, EN, DO_C, DO_A) do {                                              \
    /* 1: issue DMA for step I+5 (slot ring distance 4 from reader) */                \
    if ((I) + 5 < L) GLL((I) + 5);                                                    \
    /* 2: pack v -> bf16, 1 x ds_write_b64 (swizzled); row 4g */                      \
    {                                                                                 \
        uint2 u;                                                                      \
        u.x = cvtpk_bf16(v[0], v[1]);                                                 \
        u.y = cvtpk_bf16(v[2], v[3]);                                                 \
        Vw[wi[0]] = u;                                                                \
    }                                                                                 \
    /* 3: slot I+1 ready once <=16 DMA ops (slots I+2..I+5) remain in flight */       \
    asm volatile("s_waitcnt vmcnt(16)" ::: "memory");                                 \
    /* 4: next step's ee from LDS */                                                  \
    EESEL(EN, (I) + 1);                                                               \
    /* 5: A-fragments (conflict-free b128; same-wave DS in-order) */                  \
    const bf16x8 A0 = Vr[ra0];                                                        \
    const bf16x8 A1 = Vr[ra1];                                                        \
    /* 6: MFMA + emission/renorm multiply (C row t=0 live) */                         \
    _Pragma("unroll")                                                                 \
    for (int nt = 0; nt < 4; ++nt) {                                                  \
        f32x4 acc = {0.f, 0.f, 0.f, 0.f};                                             \
        acc = __builtin_amdgcn_mfma_f32_16x16x32_bf16(A0, Bf[nt][0], acc, 0, 0, 0);   \
        acc = __builtin_amdgcn_mfma_f32_16x16x32_bf16(A1, Bf[nt][1], acc, 0, 0, 0);   \
        float nv = acc[0] * EC[nt];                                                   \
        if (DO_A) nv *= fac;                                                          \
        v[nt] = nv;                                                                   \
    }                                                                                 \
    if (DO_A) sc += pend;                                                             \
    /* 7: renorm factor (applied next step; off critical path) */                     \
    if (DO_C) {                                                                       \
        float mx = fmaxf(fmaxf(v[0], v[1]), fmaxf(v[2], v[3]));                       \
        mx = fmaxf(mx, __shfl_xor(mx, 1, 64));                                        \
        mx = fmaxf(mx, __shfl_xor(mx, 2, 64));                                        \
        mx = fmaxf(mx, __shfl_xor(mx, 4, 64));                                        \
        mx = fmaxf(mx, __shfl_xor(mx, 8, 64));                                        \
        const unsigned ex = __float_as_uint(mx) >> 23;                                \
        fac  = __uint_as_float((254u - ex) << 23);                                    \
        pend = (float)((int)ex - 127) * LN2;                                          \
    }                                                                                 \
} while (0)

    const int S = L - 1;  // steps 1..S
    int i = 1;
    for (; i + 1 <= S; i += 2) {
        STEP(i + 0, ee1, ee0, 1, 0);  // compute renorm factor
        STEP(i + 1, ee0, ee1, 0, 1);  // apply it
    }
    if (i <= S) STEP(i, ee1, ee0, 0, 0);
#undef STEP
#undef EESEL
#undef GLL

    // final: alpha[chain] = sc + log(sum_p V) + LOG49 + (L-1)*Tmax
    float s = (v[0] + v[1]) + (v[2] + v[3]);
    s += __shfl_xor(s, 1, 64);
    s += __shfl_xor(s, 2, 64);
    s += __shfl_xor(s, 4, 64);
    s += __shfl_xor(s, 8, 64);
    const float res = sc + __logf(s) + LOG49 + (float)(L - 1) * Tmax;
    if (c0 == 0) out[b0 + g] = res;
}

extern "C" void kernel_launch(void* const* d_in, const int* in_sizes, int n_in,
                              void* d_out, int out_size, void* d_ws, size_t ws_size,
                              hipStream_t stream) {
    const float* emis = (const float*)d_in[0];
    const float* tf   = (const float*)d_in[1];
    const float* w2   = (const float*)d_in[2];
    const float* b2   = (const float*)d_in[3];
    float* out = (float*)d_out;
    float* ws  = (float*)d_ws;

    const int B = out_size;                // 8192
    const int L = in_sizes[0] / (B * TS);  // 48

    prep_kernel<<<1, 256, 0, stream>>>(tf, w2, b2, ws);
    crf_fwd<<<B / 4, 64, 0, stream>>>(emis, (const unsigned short*)ws, out, L);
}

// Round 17
// 37.663 us; speedup vs baseline: 1.2347x; 1.1053x over previous
//
#include <hip/hip_runtime.h>
#include <math.h>

#define TS 49
#define LOG49 3.8918202981106265f
#define LN2 0.6931471805599453f

typedef short bf16x8 __attribute__((ext_vector_type(8)));  // 8 bf16 = 4 VGPRs
typedef float f32x4 __attribute__((ext_vector_type(4)));
typedef float f32x4u __attribute__((ext_vector_type(4), aligned(4)));
typedef unsigned u32x4 __attribute__((ext_vector_type(4)));

// Position labeling: position p holds original state (p+1)%49 -> emission col = p.
// E stored as the A-operand of D = E * V; kappa k-labeling makes D's C-layout
// bit-identical (after bf16 pack) to the next step's B-fragment:
//   A row r = 16*nt + (lane&15); hw k = 32h + 8*(lane>>4) + s
//   kappa(32h + 8G + s) = 32h + 16*(s>>2) + 4G + (s&3)
// ws layout: bf16[nt=4][h=2][lane=64][s=8] (8 KB), then float Tmax at byte 8192.
// (identical to R14/R15 -- validated)

__global__ void prep_kernel(const float* __restrict__ tf, const float* __restrict__ w2,
                            const float* __restrict__ b2, float* __restrict__ ws) {
    __shared__ float tr[TS * TS];
    __shared__ float red[256];
    const int tid = threadIdx.x;
    const float w0 = w2[0], w1 = w2[1], w2v = w2[2], w3 = w2[3], w4 = w2[4], w5 = w2[5];
    const float bb = b2[0];
    float lmax = -INFINITY;
    for (int idx = tid; idx < TS * TS; idx += 256) {
        const float* p = tf + idx * 6;
        float s = bb + p[0]*w0 + p[1]*w1 + p[2]*w2v + p[3]*w3 + p[4]*w4 + p[5]*w5;
        tr[idx] = s;
        lmax = fmaxf(lmax, s);
    }
    red[tid] = lmax;
    __syncthreads();
    for (int s = 128; s > 0; s >>= 1) {
        if (tid < s) red[tid] = fmaxf(red[tid], red[tid + s]);
        __syncthreads();
    }
    const float Tmax = red[0];
    __syncthreads();
    unsigned short* B = (unsigned short*)ws;
    for (int idx = tid; idx < 4096; idx += 256) {
        const int s  = idx & 7;
        const int l  = (idx >> 3) & 63;
        const int h  = (idx >> 9) & 1;
        const int nt = idx >> 10;
        const int G  = l >> 4, c0 = l & 15;
        const int r  = 16 * nt + c0;                              // output position
        const int kp = 32 * h + 16 * (s >> 2) + 4 * G + (s & 3);  // input position
        float v = 0.0f;
        if (r < TS && kp < TS) {
            const int jj = (r + 1) % TS, kk = (kp + 1) % TS;
            v = __expf(tr[jj * TS + kk] - Tmax);
        }
        unsigned bts = __float_as_uint(v);
        B[idx] = (unsigned short)((bts + 0x7FFFu + ((bts >> 16) & 1u)) >> 16);  // rne bf16
    }
    if (tid == 0) ((float*)ws)[2048] = Tmax;  // byte 8192
}

__device__ __forceinline__ unsigned cvtpk_bf16(float lo, float hi) {
    unsigned d;  // D[15:0]=bf16(lo), D[31:16]=bf16(hi)
    asm("v_cvt_pk_bf16_f32 %0, %1, %2" : "=v"(d) : "v"(lo), "v"(hi));
    return d;
}

// One wave = 4 real chains (chain = (lane&15)&3; MFMA cols 4..15 redundant copies).
// State in C-layout regs v[nt][t]: position 16nt+4G+t (G=lane>>4), col c0.
// Critical path: mul -> cvt_pk -> 2-deep MFMA. No LDS on the state path.
// Emissions: ONE dwordx4/wave/step (load role: lane (g=G, c0) loads chain g's
// cols 4c0..4c0+3, edge c0>=12 -> 45..48), bounced via a 2KB swizzled LDS buffer
// EB[2][4][64] (chunk ^ (chain<<2) swizzle -> <=2-way banks both sides) into the
// kappa lane layout; all staging is off the critical path (1 step of slack).
__global__ __launch_bounds__(64, 2) void crf_fwd(const float* __restrict__ emis,
                                                 const unsigned short* __restrict__ wsE,
                                                 float* __restrict__ out, int L) {
    __shared__ __align__(16) float EB[2][4][64];  // 2 KB
    const int l = threadIdx.x, G = l >> 4, c0 = l & 15;
    const int cc = c0 & 3;
    const int b0 = blockIdx.x * 4;
    const float Tmax = ((const float*)wsE)[2048];
    float* const EBf = &EB[0][0][0];

    // E A-fragments, register-resident (AGPR residency is fine: MFMA-only use)
    bf16x8 E[4][2];
    {
        const bf16x8* Et = (const bf16x8*)wsE;
        #pragma unroll
        for (int nt = 0; nt < 4; ++nt)
            #pragma unroll
            for (int h = 0; h < 2; ++h) E[nt][h] = Et[(nt * 2 + h) * 64 + l];
    }

    // zero pad cols 49..63 of both slots (exp(0)=1, annihilated by zero E rows)
    for (int z = l; z < 120; z += 64) {
        const int slot = z / 60, r = z - slot * 60;
        const int ch = r / 15, c = 49 + (r - ch * 15);
        const int chunk = c >> 2, rem = c & 3;
        EBf[slot * 256 + ch * 64 + ((chunk ^ (ch << 2)) << 2) + rem] = 0.0f;
    }

    // load-role addressing: lane (g=G, c0) loads chain b0+g, cols col4..col4+3
    const int LT = L * TS;
    const bool c12 = (c0 >= 12);
    const int col4 = c12 ? 45 : 4 * c0;
    const float* const eb = emis + (size_t)(b0 + G) * LT + col4;

    // write addresses (float index): chunk c0 of chain G (c0<12); col48 (c0==12)
    const int wce = G * 64 + ((c0 ^ (G << 2)) << 2);
    const int w48 = G * 64 + ((12 ^ (G << 2)) << 2);
    // read addresses: chunk (4nt+G) of chain cc
    int rix[4];
    #pragma unroll
    for (int nt = 0; nt < 4; ++nt)
        rix[nt] = cc * 64 + (((4 * nt + G) ^ (cc << 2)) << 2);

    f32x4 r4[4];  // load ring, statically indexed

#define LQ(STEP, SLOT) do { r4[SLOT] = *(const f32x4u*)(eb + (STEP) * TS); } while (0)

#define WR(EBS, SLOT) do {                                                            \
    asm volatile("" : "+v"(r4[SLOT]));  /* force arch-VGPR here (write site) */       \
    float* _d = EBf + ((EBS) << 8);                                                   \
    if (!c12) *(f32x4*)(_d + wce) = r4[SLOT];                                         \
    else if (c0 == 12) _d[w48] = r4[SLOT].w;                                          \
} while (0)

#define EESEL(DST, EBS) do {                                                          \
    const float* _s = EBf + ((EBS) << 8);                                             \
    _Pragma("unroll")                                                                 \
    for (int nt = 0; nt < 4; ++nt) {                                                  \
        const f32x4 q = *(const f32x4*)(_s + rix[nt]);                                \
        DST[nt][0] = __expf(q.x);                                                     \
        DST[nt][1] = __expf(q.y);                                                     \
        DST[nt][2] = __expf(q.z);                                                     \
        DST[nt][3] = __expf(q.w);                                                     \
    }                                                                                 \
} while (0)

    f32x4 acc[4];
    float v[4][4];
    float ee0[4][4], ee1[4][4];
    float sc = 0.f, fac = 1.f, pend = 0.f;

#define PACKMM() do {                                                                 \
    u32x4 Bu0, Bu1;                                                                   \
    Bu0.x = cvtpk_bf16(v[0][0], v[0][1]);                                             \
    Bu0.y = cvtpk_bf16(v[0][2], v[0][3]);                                             \
    Bu0.z = cvtpk_bf16(v[1][0], v[1][1]);                                             \
    Bu0.w = cvtpk_bf16(v[1][2], v[1][3]);                                             \
    Bu1.x = cvtpk_bf16(v[2][0], v[2][1]);                                             \
    Bu1.y = cvtpk_bf16(v[2][2], v[2][3]);                                             \
    Bu1.z = cvtpk_bf16(v[3][0], v[3][1]);                                             \
    Bu1.w = cvtpk_bf16(v[3][2], v[3][3]);                                             \
    const bf16x8 B0 = __builtin_bit_cast(bf16x8, Bu0);                                \
    const bf16x8 B1 = __builtin_bit_cast(bf16x8, Bu1);                                \
    const f32x4 z_ = {0.f, 0.f, 0.f, 0.f};                                            \
    _Pragma("unroll")                                                                 \
    for (int nt = 0; nt < 4; ++nt) {                                                  \
        f32x4 a = __builtin_amdgcn_mfma_f32_16x16x32_bf16(E[nt][0], B0, z_, 0, 0, 0); \
        a = __builtin_amdgcn_mfma_f32_16x16x32_bf16(E[nt][1], B1, a, 0, 0, 0);        \
        acc[nt] = a;                                                                  \
    }                                                                                 \
} while (0)

#define RENC() do {                                                                   \
    float mx = v[0][0];                                                               \
    _Pragma("unroll")                                                                 \
    for (int nt = 0; nt < 4; ++nt)                                                    \
        _Pragma("unroll")                                                             \
        for (int t = 0; t < 4; ++t) mx = fmaxf(mx, v[nt][t]);                         \
    mx = fmaxf(mx, __shfl_xor(mx, 16, 64));                                           \
    mx = fmaxf(mx, __shfl_xor(mx, 32, 64));                                           \
    const unsigned ex = __float_as_uint(mx) >> 23;                                    \
    fac  = __uint_as_float((254u - ex) << 23);                                        \
    pend = (float)((int)ex - 127) * LN2;                                              \
} while (0)

#define STEP(I, EC, EN, LQS, WRS, EBS, DO_C, DO_A) do {                               \
    if ((I) + 3 < L) LQ((I) + 3, LQS);                                                \
    asm volatile("" ::: "memory");                                                    \
    if ((I) + 1 < L) WR(EBS, WRS);   /* row I+1, loaded 2 steps ago */                \
    asm volatile("" ::: "memory");                                                    \
    _Pragma("unroll")                                                                 \
    for (int nt = 0; nt < 4; ++nt)                                                    \
        _Pragma("unroll")                                                             \
        for (int t = 0; t < 4; ++t) {                                                 \
            float nv = acc[nt][t] * EC[nt][t];                                        \
            if (DO_A) nv *= fac;                                                      \
            v[nt][t] = nv;                                                            \
        }                                                                             \
    if (DO_A) sc += pend;                                                             \
    PACKMM();                                                                         \
    if ((I) + 1 < L) EESEL(EN, EBS);  /* read what WR wrote ~60 instrs ago */         \
    if (DO_C) RENC();                                                                 \
} while (0)

    // prologue: rows 0..3 into the ring
    LQ(0, 0);
    if (L > 1) LQ(1, 1);
    if (L > 2) LQ(2, 2);
    if (L > 3) LQ(3, 3);
    asm volatile("" ::: "memory");
    WR(0, 0);  // row 0 -> EB[0]
    asm volatile("" ::: "memory");
    // init V_0 from EB[0]: v = exp(emit[0][p]); dead positions (p>=49) = 0
    #pragma unroll
    for (int nt = 0; nt < 3; ++nt) {
        const f32x4 q = *(const f32x4*)(EBf + rix[nt]);
        v[nt][0] = __expf(q.x);
        v[nt][1] = __expf(q.y);
        v[nt][2] = __expf(q.z);
        v[nt][3] = __expf(q.w);
    }
    {
        const f32x4 q = *(const f32x4*)(EBf + rix[3]);
        v[3][0] = (G == 0) ? __expf(q.x) : 0.0f;  // p=48 only at (G=0,t=0)
        v[3][1] = 0.0f; v[3][2] = 0.0f; v[3][3] = 0.0f;
    }
    if (L > 1) WR(1, 1);  // row 1 -> EB[1]
    asm volatile("" ::: "memory");
    if (L > 1) EESEL(ee1, 1);  // ee for step 1
    PACKMM();                  // acc = E @ V_0
    asm volatile("" ::: "memory");

    const int S = L - 1;  // steps 1..S
    int i = 1;
    for (; i + 3 <= S; i += 4) {  // i == 1 mod 4 -> static slots per position
        STEP(i + 0, ee1, ee0, 0, 2, 0, 1, 0);
        STEP(i + 1, ee0, ee1, 1, 3, 1, 0, 1);
        STEP(i + 2, ee1, ee0, 2, 0, 0, 0, 0);
        STEP(i + 3, ee0, ee1, 3, 1, 1, 0, 0);
    }
    if (i <= S)     STEP(i,     ee1, ee0, 0, 2, 0, 1, 0);
    if (i + 1 <= S) STEP(i + 1, ee0, ee1, 1, 3, 1, 0, 1);
    if (i + 2 <= S) STEP(i + 2, ee1, ee0, 2, 0, 0, 0, 0);
#undef STEP
#undef RENC
#undef PACKMM
#undef EESEL
#undef WR
#undef LQ

    // final: alpha[chain] = sc + log(sum_pos V) + LOG49 + (L-1)*Tmax
    float s = 0.0f;
    #pragma unroll
    for (int nt = 0; nt < 4; ++nt)
        #pragma unroll
        for (int t = 0; t < 4; ++t) s += v[nt][t];
    s += __shfl_xor(s, 16, 64);
    s += __shfl_xor(s, 32, 64);
    const float res = sc + __logf(s) + LOG49 + (float)(L - 1) * Tmax;
    if (l < 4) out[b0 + l] = res;
}

extern "C" void kernel_launch(void* const* d_in, const int* in_sizes, int n_in,
                              void* d_out, int out_size, void* d_ws, size_t ws_size,
                              hipStream_t stream) {
    const float* emis = (const float*)d_in[0];
    const float* tf   = (const float*)d_in[1];
    const float* w2   = (const float*)d_in[2];
    const float* b2   = (const float*)d_in[3];
    float* out = (float*)d_out;
    float* ws  = (float*)d_ws;

    const int B = out_size;                // 8192
    const int L = in_sizes[0] / (B * TS);  // 48

    prep_kernel<<<1, 256, 0, stream>>>(tf, w2, b2, ws);
    crf_fwd<<<B / 4, 64, 0, stream>>>(emis, (const unsigned short*)ws, out, L);
}

// Round 18
// 34.412 us; speedup vs baseline: 1.3514x; 1.0945x over previous
//
#include <hip/hip_runtime.h>
#include <math.h>

#define TS 49
#define LOG49 3.8918202981106265f
#define LN2 0.6931471805599453f

typedef short bf16x8 __attribute__((ext_vector_type(8)));  // 8 bf16 = 4 VGPRs
typedef float f32x4 __attribute__((ext_vector_type(4)));
typedef float f32x4u __attribute__((ext_vector_type(4), aligned(4)));

// State relabeling: position p holds original state (p+1)%49 -> emission col = p.
// ws layout (identical to R8/R12/R13 -- validated):
//   bytes [0, 8192): B-fragments bf16[nt=4][h=2][lane=64][s=8]
//     value = exp(trans[(jp+1)%49][(kp+1)%49] - Tmax), jp = 4*(lane&15)+nt (out pos),
//     kp = 32*h + 8*(lane>>4) + s (in pos); zero outside jp<49 && kp<49.
//   byte 8192: float Tmax

__global__ void prep_kernel(const float* __restrict__ tf, const float* __restrict__ w2,
                            const float* __restrict__ b2, float* __restrict__ ws) {
    __shared__ float tr[TS * TS];
    __shared__ float red[256];
    const int tid = threadIdx.x;
    const float w0 = w2[0], w1 = w2[1], w2v = w2[2], w3 = w2[3], w4 = w2[4], w5 = w2[5];
    const float bb = b2[0];
    float lmax = -INFINITY;
    for (int idx = tid; idx < TS * TS; idx += 256) {
        const float* p = tf + idx * 6;
        float s = bb + p[0]*w0 + p[1]*w1 + p[2]*w2v + p[3]*w3 + p[4]*w4 + p[5]*w5;
        tr[idx] = s;
        lmax = fmaxf(lmax, s);
    }
    red[tid] = lmax;
    __syncthreads();
    for (int s = 128; s > 0; s >>= 1) {
        if (tid < s) red[tid] = fmaxf(red[tid], red[tid + s]);
        __syncthreads();
    }
    const float Tmax = red[0];
    __syncthreads();
    unsigned short* B = (unsigned short*)ws;
    for (int idx = tid; idx < 4096; idx += 256) {
        const int s  = idx & 7;
        const int l  = (idx >> 3) & 63;
        const int h  = (idx >> 9) & 1;
        const int nt = idx >> 10;
        const int jp = 4 * (l & 15) + nt;
        const int kp = 32 * h + 8 * (l >> 4) + s;
        float v = 0.0f;
        if (jp < TS && kp < TS) {
            const int jj = (jp + 1) % TS, kk = (kp + 1) % TS;
            v = __expf(tr[jj * TS + kk] - Tmax);
        }
        unsigned bts = __float_as_uint(v);
        B[idx] = (unsigned short)((bts + 0x7FFFu + ((bts >> 16) & 1u)) >> 16);  // rne bf16
    }
    if (tid == 0) ((float*)ws)[2048] = Tmax;  // byte 8192
}

__device__ __forceinline__ unsigned cvtpk_bf16(float lo, float hi) {
    unsigned d;  // D[15:0]=bf16(lo), D[31:16]=bf16(hi)
    asm("v_cvt_pk_bf16_f32 %0, %1, %2" : "=v"(d) : "v"(lo), "v"(hi));
    return d;
}

// One wave = 2 REAL chains (groups g=0,1); groups g=2,3 compute duplicates of
// chains 0,1 (same cache lines -> zero extra HBM traffic; matrix pipe has
// headroom). This halves chains/wave vs R13 purely to double resident waves:
// grid 4096 blocks = 16/CU = 4 waves/SIMD, hiding the per-step load latency
// that AGPR-parking makes unhidable within one wave.
// Position p = 4*(lane&15)+nt. V16: chain-major [16][64 bf16], XOR-swizzled.
__global__ __launch_bounds__(64, 4) void crf_fwd(const float* __restrict__ emis,
                                                 const unsigned short* __restrict__ wsB,
                                                 float* __restrict__ out, int L) {
    __shared__ __align__(16) unsigned short V16[1024];
    const int l = threadIdx.x, g = l >> 4, c0 = l & 15;
    const int b0 = blockIdx.x * 2;
    const float Tmax = ((const float*)wsB)[2048];

    // E fragments (B-operand), register-resident
    bf16x8 Bf[4][2];
    {
        const bf16x8* Bt = (const bf16x8*)wsB;
        #pragma unroll
        for (int nt = 0; nt < 4; ++nt)
            #pragma unroll
            for (int h = 0; h < 2; ++h) Bf[nt][h] = Bt[(nt * 2 + h) * 64 + l];
    }

    // V16 LDS indices (R8-validated swizzle)
    int wi[4];
    #pragma unroll
    for (int t = 0; t < 4; ++t) {
        const int ch = 4 * g + t;
        wi[t] = ch * 16 + (c0 ^ ((ch & 7) << 1));  // uint2 units
    }
    const int ra0 = c0 * 8 + (g ^ (c0 & 7));        // bf16x8 units, k 0..31
    const int ra1 = c0 * 8 + ((4 + g) ^ (c0 & 7));  // k 32..63
    uint2* const Vw = (uint2*)V16;
    const bf16x8* const Vr = (const bf16x8*)V16;

    // zero dead internal rows (t=1..3) once
    {
        const uint2 z = {0u, 0u};
        Vw[wi[1]] = z;
        Vw[wi[2]] = z;
        Vw[wi[3]] = z;
    }

    // Emission addressing: chain (g&1); duplicate groups hit identical lines.
    const int LT = L * TS;
    const bool sel12 = (c0 >= 12);
    const int col4 = sel12 ? 45 : 4 * c0;
    const float* const ebase = emis + (size_t)(b0 + (g & 1)) * LT + col4;

    f32x4 pf[4];  // [slot], statically indexed only

#define LQ(STEP, SLOT) do {                                                           \
    pf[SLOT] = *(const f32x4u*)(ebase + (STEP) * TS);                                 \
} while (0)

#define EESEL(DST, SLOT) do {                                                         \
    const f32x4 q = pf[SLOT];                                                         \
    DST[0] = __expf(sel12 ? q.w : q.x);                                               \
    DST[1] = __expf(q.y);                                                             \
    DST[2] = __expf(q.z);                                                             \
    DST[3] = __expf(q.w);                                                             \
} while (0)

    // prologue: fill 4 slots
    LQ(0, 0);
    if (L > 1) LQ(1, 1);
    if (L > 2) LQ(2, 2);
    if (L > 3) LQ(3, 3);

    // init V_0 from slot 0: v = exp(emit[0][p]), dead positions -> 0
    float v[4];
    {
        const f32x4 q = pf[0];
        const float i0 = sel12 ? q.w : q.x;
        v[0] = (4 * c0 + 0 < TS) ? __expf(i0)  : 0.0f;
        v[1] = (4 * c0 + 1 < TS) ? __expf(q.y) : 0.0f;
        v[2] = (4 * c0 + 2 < TS) ? __expf(q.z) : 0.0f;
        v[3] = (4 * c0 + 3 < TS) ? __expf(q.w) : 0.0f;
    }

    float ee0[4], ee1[4];
    EESEL(ee1, 1);  // emissions for step 1

    float sc = 0.f, fac = 1.f, pend = 0.f;

#define STEP(I, EC, EN, SN, SL, DO_C, DO_A) do {                                      \
    /* 1: pack v -> bf16, 1 x ds_write_b64 (swizzled); row 4g */                      \
    {                                                                                 \
        uint2 u;                                                                      \
        u.x = cvtpk_bf16(v[0], v[1]);                                                 \
        u.y = cvtpk_bf16(v[2], v[3]);                                                 \
        Vw[wi[0]] = u;                                                                \
    }                                                                                 \
    /* 2: next step's ee (pads DS drain; loads landed >=2 steps ago) */               \
    EESEL(EN, SN);                                                                    \
    /* 3: issue loads for step I+3 into the freed slot */                             \
    if ((I) + 3 < L) LQ((I) + 3, SL);                                                 \
    asm volatile("" ::: "memory");                                                    \
    /* 4: A-fragments (conflict-free b128; same-wave DS in-order) */                  \
    const bf16x8 A0 = Vr[ra0];                                                        \
    const bf16x8 A1 = Vr[ra1];                                                        \
    /* 5+6: MFMA + emission/renorm multiply (C row t=0 live) */                       \
    _Pragma("unroll")                                                                 \
    for (int nt = 0; nt < 4; ++nt) {                                                  \
        f32x4 acc = {0.f, 0.f, 0.f, 0.f};                                             \
        acc = __builtin_amdgcn_mfma_f32_16x16x32_bf16(A0, Bf[nt][0], acc, 0, 0, 0);   \
        acc = __builtin_amdgcn_mfma_f32_16x16x32_bf16(A1, Bf[nt][1], acc, 0, 0, 0);   \
        float nv = acc[0] * EC[nt];                                                   \
        if (DO_A) nv *= fac;                                                          \
        v[nt] = nv;                                                                   \
    }                                                                                 \
    if (DO_A) sc += pend;                                                             \
    /* 7: renorm factor (applied next step; off critical path) */                     \
    if (DO_C) {                                                                       \
        float mx = fmaxf(fmaxf(v[0], v[1]), fmaxf(v[2], v[3]));                       \
        mx = fmaxf(mx, __shfl_xor(mx, 1, 64));                                        \
        mx = fmaxf(mx, __shfl_xor(mx, 2, 64));                                        \
        mx = fmaxf(mx, __shfl_xor(mx, 4, 64));                                        \
        mx = fmaxf(mx, __shfl_xor(mx, 8, 64));                                        \
        const unsigned ex = __float_as_uint(mx) >> 23;                                \
        fac  = __uint_as_float((254u - ex) << 23);                                    \
        pend = (float)((int)ex - 127) * LN2;                                          \
    }                                                                                 \
} while (0)

    const int S = L - 1;  // steps 1..S
    int i = 1;
    for (; i + 3 <= S; i += 4) {  // i == 1 mod 4 -> static pf slots
        STEP(i + 0, ee1, ee0, 2, 0, 1, 0);
        STEP(i + 1, ee0, ee1, 3, 1, 0, 1);
        STEP(i + 2, ee1, ee0, 0, 2, 0, 0);
        STEP(i + 3, ee0, ee1, 1, 3, 0, 0);
    }
    if (i <= S)     STEP(i,     ee1, ee0, 2, 0, 1, 0);
    if (i + 1 <= S) STEP(i + 1, ee0, ee1, 3, 1, 0, 1);
    if (i + 2 <= S) STEP(i + 2, ee1, ee0, 0, 2, 0, 0);
#undef STEP
#undef EESEL
#undef LQ

    // final: alpha[chain] = sc + log(sum_p V) + LOG49 + (L-1)*Tmax
    float s = (v[0] + v[1]) + (v[2] + v[3]);
    s += __shfl_xor(s, 1, 64);
    s += __shfl_xor(s, 2, 64);
    s += __shfl_xor(s, 4, 64);
    s += __shfl_xor(s, 8, 64);
    const float res = sc + __logf(s) + LOG49 + (float)(L - 1) * Tmax;
    if (c0 == 0 && g < 2) out[b0 + g] = res;
}

extern "C" void kernel_launch(void* const* d_in, const int* in_sizes, int n_in,
                              void* d_out, int out_size, void* d_ws, size_t ws_size,
                              hipStream_t stream) {
    const float* emis = (const float*)d_in[0];
    const float* tf   = (const float*)d_in[1];
    const float* w2   = (const float*)d_in[2];
    const float* b2   = (const float*)d_in[3];
    float* out = (float*)d_out;
    float* ws  = (float*)d_ws;

    const int B = out_size;                // 8192
    const int L = in_sizes[0] / (B * TS);  // 48

    prep_kernel<<<1, 256, 0, stream>>>(tf, w2, b2, ws);
    crf_fwd<<<B / 2, 64, 0, stream>>>(emis, (const unsigned short*)ws, out, L);
}

// Round 19
// 28.097 us; speedup vs baseline: 1.6551x; 1.2248x over previous
//
#include <hip/hip_runtime.h>
#include <math.h>

#define TS 49
#define LOG49 3.8918202981106265f
#define LN2 0.6931471805599453f

typedef short bf16x8 __attribute__((ext_vector_type(8)));  // 8 bf16 = 4 VGPRs
typedef float f32x4 __attribute__((ext_vector_type(4)));
typedef float f32x4u __attribute__((ext_vector_type(4), aligned(4)));

// State relabeling: position p holds original state (p+1)%49 -> emission col = p.
// ws layout (identical to R8/R12/R13 -- validated):
//   bytes [0, 8192): B-fragments bf16[nt=4][h=2][lane=64][s=8]
//     value = exp(trans[(jp+1)%49][(kp+1)%49] - Tmax), jp = 4*(lane&15)+nt (out pos),
//     kp = 32*h + 8*(lane>>4) + s (in pos); zero outside jp<49 && kp<49.
//   byte 8192: float Tmax

__global__ void prep_kernel(const float* __restrict__ tf, const float* __restrict__ w2,
                            const float* __restrict__ b2, float* __restrict__ ws) {
    __shared__ float tr[TS * TS];
    __shared__ float red[256];
    const int tid = threadIdx.x;
    const float w0 = w2[0], w1 = w2[1], w2v = w2[2], w3 = w2[3], w4 = w2[4], w5 = w2[5];
    const float bb = b2[0];
    float lmax = -INFINITY;
    for (int idx = tid; idx < TS * TS; idx += 256) {
        const float* p = tf + idx * 6;
        float s = bb + p[0]*w0 + p[1]*w1 + p[2]*w2v + p[3]*w3 + p[4]*w4 + p[5]*w5;
        tr[idx] = s;
        lmax = fmaxf(lmax, s);
    }
    red[tid] = lmax;
    __syncthreads();
    for (int s = 128; s > 0; s >>= 1) {
        if (tid < s) red[tid] = fmaxf(red[tid], red[tid + s]);
        __syncthreads();
    }
    const float Tmax = red[0];
    __syncthreads();
    unsigned short* B = (unsigned short*)ws;
    for (int idx = tid; idx < 4096; idx += 256) {
        const int s  = idx & 7;
        const int l  = (idx >> 3) & 63;
        const int h  = (idx >> 9) & 1;
        const int nt = idx >> 10;
        const int jp = 4 * (l & 15) + nt;
        const int kp = 32 * h + 8 * (l >> 4) + s;
        float v = 0.0f;
        if (jp < TS && kp < TS) {
            const int jj = (jp + 1) % TS, kk = (kp + 1) % TS;
            v = __expf(tr[jj * TS + kk] - Tmax);
        }
        unsigned bts = __float_as_uint(v);
        B[idx] = (unsigned short)((bts + 0x7FFFu + ((bts >> 16) & 1u)) >> 16);  // rne bf16
    }
    if (tid == 0) ((float*)ws)[2048] = Tmax;  // byte 8192
}

__device__ __forceinline__ unsigned cvtpk_bf16(float lo, float hi) {
    unsigned d;  // D[15:0]=bf16(lo), D[31:16]=bf16(hi)
    asm("v_cvt_pk_bf16_f32 %0, %1, %2" : "=v"(d) : "v"(lo), "v"(hi));
    return d;
}

// R13 core (4 chains/wave, 2048 blocks = 2 waves/SIMD), with emissions loaded in
// 4-STEP GROUPS: two 4-slot register banks (pA/pB) ping-pong; a bank is refilled
// with group g+2 by 4 back-to-back dwordx4 at the last step of group g, and first
// consumed 4 steps later -> at most ONE exposed load-latency per 4 steps (vs 4 in
// R13), regardless of whether the allocator makes loads synchronous.
__global__ __launch_bounds__(64, 2) void crf_fwd(const float* __restrict__ emis,
                                                 const unsigned short* __restrict__ wsB,
                                                 float* __restrict__ out, int L) {
    __shared__ __align__(16) unsigned short V16[1024];
    const int l = threadIdx.x, g = l >> 4, c0 = l & 15;
    const int b0 = blockIdx.x * 4;
    const float Tmax = ((const float*)wsB)[2048];

    // E fragments (B-operand), register-resident
    bf16x8 Bf[4][2];
    {
        const bf16x8* Bt = (const bf16x8*)wsB;
        #pragma unroll
        for (int nt = 0; nt < 4; ++nt)
            #pragma unroll
            for (int h = 0; h < 2; ++h) Bf[nt][h] = Bt[(nt * 2 + h) * 64 + l];
    }

    // V16 LDS indices (validated swizzle)
    int wi[4];
    #pragma unroll
    for (int t = 0; t < 4; ++t) {
        const int ch = 4 * g + t;
        wi[t] = ch * 16 + (c0 ^ ((ch & 7) << 1));  // uint2 units
    }
    const int ra0 = c0 * 8 + (g ^ (c0 & 7));        // bf16x8 units, k 0..31
    const int ra1 = c0 * 8 + ((4 + g) ^ (c0 & 7));  // k 32..63
    uint2* const Vw = (uint2*)V16;
    const bf16x8* const Vr = (const bf16x8*)V16;

    // zero dead internal rows (t=1..3) once
    {
        const uint2 z = {0u, 0u};
        Vw[wi[1]] = z;
        Vw[wi[2]] = z;
        Vw[wi[3]] = z;
    }

    // Emission addressing: chain b0+g, cols col4..col4+3 (edge lanes clamp to 45).
    const int LT = L * TS;
    const bool sel12 = (c0 >= 12);
    const int col4 = sel12 ? 45 : 4 * c0;
    const float* const ebase = emis + (size_t)(b0 + g) * LT + col4;

    f32x4 pA[4], pB[4];  // two 4-step banks, statically indexed only

#define LQ4(BNK, GRP) do {                                                            \
    const int _b = 4 * (GRP);                                                         \
    if (_b < L) {                                                                     \
        BNK[0] = *(const f32x4u*)(ebase + (_b + 0) * TS);                             \
        BNK[1] = *(const f32x4u*)(ebase + (_b + 1) * TS);                             \
        BNK[2] = *(const f32x4u*)(ebase + (_b + 2) * TS);                             \
        BNK[3] = *(const f32x4u*)(ebase + (_b + 3) * TS);                             \
    }                                                                                 \
} while (0)

#define EESEL(DST, BNK, PN) do {                                                      \
    const f32x4 q = BNK[PN];                                                          \
    DST[0] = __expf(sel12 ? q.w : q.x);                                               \
    DST[1] = __expf(q.y);                                                             \
    DST[2] = __expf(q.z);                                                             \
    DST[3] = __expf(q.w);                                                             \
} while (0)

    // prologue: bank A <- group 0 (steps 0..3), bank B <- group 1 (steps 4..7)
    LQ4(pA, 0);
    LQ4(pB, 1);

    // init V_0 from pA[0]: v = exp(emit[0][p]), dead positions -> 0
    float v[4];
    {
        const f32x4 q = pA[0];
        const float i0 = sel12 ? q.w : q.x;
        v[0] = (4 * c0 + 0 < TS) ? __expf(i0)  : 0.0f;
        v[1] = (4 * c0 + 1 < TS) ? __expf(q.y) : 0.0f;
        v[2] = (4 * c0 + 2 < TS) ? __expf(q.z) : 0.0f;
        v[3] = (4 * c0 + 3 < TS) ? __expf(q.w) : 0.0f;
    }

    float ee0[4], ee1[4];
    EESEL(ee1, pA, 1);  // emissions for step 1

    float sc = 0.f, fac = 1.f, pend = 0.f;

// EC: ee consumed this step. EN: ee produced for step I+1 from BNK[PN].
// DO_RF: refill RBNK with group RGRP (4 back-to-back loads, one drain later).
#define STEP(I, EC, EN, BNK, PN, DO_C, DO_A, DO_RF, RBNK, RGRP) do {                  \
    /* 1: pack v -> bf16, 1 x ds_write_b64 (swizzled); row 4g */                      \
    {                                                                                 \
        uint2 u;                                                                      \
        u.x = cvtpk_bf16(v[0], v[1]);                                                 \
        u.y = cvtpk_bf16(v[2], v[3]);                                                 \
        Vw[wi[0]] = u;                                                                \
    }                                                                                 \
    /* 2: next step's ee (bank data landed >=4 steps ago) */                          \
    if ((I) + 1 < L) EESEL(EN, BNK, PN);                                              \
    /* 3: group refill (only at pos-3 steps) */                                       \
    if (DO_RF) LQ4(RBNK, RGRP);                                                       \
    asm volatile("" ::: "memory");                                                    \
    /* 4: A-fragments (conflict-free b128; same-wave DS in-order) */                  \
    const bf16x8 A0 = Vr[ra0];                                                        \
    const bf16x8 A1 = Vr[ra1];                                                        \
    /* 5+6: MFMA + emission/renorm multiply (C row t=0 live) */                       \
    _Pragma("unroll")                                                                 \
    for (int nt = 0; nt < 4; ++nt) {                                                  \
        f32x4 acc = {0.f, 0.f, 0.f, 0.f};                                             \
        acc = __builtin_amdgcn_mfma_f32_16x16x32_bf16(A0, Bf[nt][0], acc, 0, 0, 0);   \
        acc = __builtin_amdgcn_mfma_f32_16x16x32_bf16(A1, Bf[nt][1], acc, 0, 0, 0);   \
        float nv = acc[0] * EC[nt];                                                   \
        if (DO_A) nv *= fac;                                                          \
        v[nt] = nv;                                                                   \
    }                                                                                 \
    if (DO_A) sc += pend;                                                             \
    /* 7: renorm factor (applied next step; off critical path) */                     \
    if (DO_C) {                                                                       \
        float mx = fmaxf(fmaxf(v[0], v[1]), fmaxf(v[2], v[3]));                       \
        mx = fmaxf(mx, __shfl_xor(mx, 1, 64));                                        \
        mx = fmaxf(mx, __shfl_xor(mx, 2, 64));                                        \
        mx = fmaxf(mx, __shfl_xor(mx, 4, 64));                                        \
        mx = fmaxf(mx, __shfl_xor(mx, 8, 64));                                        \
        const unsigned ex = __float_as_uint(mx) >> 23;                                \
        fac  = __uint_as_float((254u - ex) << 23);                                    \
        pend = (float)((int)ex - 127) * LN2;                                          \
    }                                                                                 \
} while (0)

    const int S = L - 1;  // steps 1..S (L = 48 -> S = 47, groups 0..11)

    // group 0 remainder: steps 1..3 (bank A); refill A <- group 2 at pos 3
    if (1 <= S) STEP(1, ee1, ee0, pA, 2, 1, 0, 0, pA, 0);
    if (2 <= S) STEP(2, ee0, ee1, pA, 3, 0, 1, 0, pA, 0);
    if (3 <= S) STEP(3, ee1, ee0, pB, 0, 0, 0, 1, pA, 2);

    // main: two groups (8 steps) per iteration; gg odd -> bank B, gg+1 -> bank A
    int gg = 1;
    for (; 4 * gg + 7 <= S; gg += 2) {
        const int s4 = 4 * gg;
        STEP(s4 + 0, ee0, ee1, pB, 1, 1, 0, 0, pB, 0);
        STEP(s4 + 1, ee1, ee0, pB, 2, 0, 1, 0, pB, 0);
        STEP(s4 + 2, ee0, ee1, pB, 3, 0, 0, 0, pB, 0);
        STEP(s4 + 3, ee1, ee0, pA, 0, 0, 0, 1, pB, gg + 2);
        STEP(s4 + 4, ee0, ee1, pA, 1, 1, 0, 0, pA, 0);
        STEP(s4 + 5, ee1, ee0, pA, 2, 0, 1, 0, pA, 0);
        STEP(s4 + 6, ee0, ee1, pA, 3, 0, 0, 0, pA, 0);
        STEP(s4 + 7, ee1, ee0, pB, 0, 0, 0, 1, pA, gg + 3);
    }

    // tail group (bank B if gg odd -- for L=48, gg=11, steps 44..47)
    {
        const int s4 = 4 * gg;
        if (s4 + 0 <= S) STEP(s4 + 0, ee0, ee1, pB, 1, 1, 0, 0, pB, 0);
        if (s4 + 1 <= S) STEP(s4 + 1, ee1, ee0, pB, 2, 0, 1, 0, pB, 0);
        if (s4 + 2 <= S) STEP(s4 + 2, ee0, ee1, pB, 3, 0, 0, 0, pB, 0);
        if (s4 + 3 <= S) STEP(s4 + 3, ee1, ee0, pB, 0, 0, 0, 0, pB, 0);
    }
#undef STEP
#undef EESEL
#undef LQ4

    // final: alpha[chain] = sc + log(sum_p V) + LOG49 + (L-1)*Tmax
    float s = (v[0] + v[1]) + (v[2] + v[3]);
    s += __shfl_xor(s, 1, 64);
    s += __shfl_xor(s, 2, 64);
    s += __shfl_xor(s, 4, 64);
    s += __shfl_xor(s, 8, 64);
    const float res = sc + __logf(s) + LOG49 + (float)(L - 1) * Tmax;
    if (c0 == 0) out[b0 + g] = res;
}

extern "C" void kernel_launch(void* const* d_in, const int* in_sizes, int n_in,
                              void* d_out, int out_size, void* d_ws, size_t ws_size,
                              hipStream_t stream) {
    const float* emis = (const float*)d_in[0];
    const float* tf   = (const float*)d_in[1];
    const float* w2   = (const float*)d_in[2];
    const float* b2   = (const float*)d_in[3];
    float* out = (float*)d_out;
    float* ws  = (float*)d_ws;

    const int B = out_size;                // 8192
    const int L = in_sizes[0] / (B * TS);  // 48

    prep_kernel<<<1, 256, 0, stream>>>(tf, w2, b2, ws);
    crf_fwd<<<B / 4, 64, 0, stream>>>(emis, (const unsigned short*)ws, out, L);
}